// Round 6
// baseline (350.412 us; speedup 1.0000x reference)
//
#include <hip/hip_runtime.h>

// Problem constants
#define HS 256
#define W3 768              // 3*H
#define CCH 56              // C = C_FEAT + N_PARTS
#define CF 32               // C_FEAT
#define NP 24               // N_PARTS
#define NPTS 8192
#define NPOINTS (4 * NPTS)  // 32768 global points
#define PLANE_SZ (HS * W3)  // 196608 floats per (b, c) slab
#define PQ (PLANE_SZ / 4)   // 49152 float4 per plane

// ---------------- Kernel F: build fused (mean, logit) planes ----------------
// F[b][part][y][x3] = float2(mean_c<32 tri[b,c,y,x3], tri[b,CF+part,y,x3])
// One thread per float4 of a (b) plane; writes 24 parts x 32 B contiguous.
__global__ __launch_bounds__(256) void tp_fuse_kernel(
    const float* __restrict__ tri, float* __restrict__ F) {
    const int t = blockIdx.x * 256 + threadIdx.x;  // [0, 4*PQ)
    const int b = t / PQ;
    const int rem = t - b * PQ;
    const float4* __restrict__ base = (const float4*)tri + (size_t)b * CCH * PQ;

    float4 acc = {0.f, 0.f, 0.f, 0.f};
#pragma unroll
    for (int c = 0; c < CF; ++c) {
        float4 v = base[(size_t)c * PQ + rem];
        acc.x += v.x; acc.y += v.y; acc.z += v.z; acc.w += v.w;
    }
    const float s = 1.0f / (float)CF;
    acc.x *= s; acc.y *= s; acc.z *= s; acc.w *= s;

#pragma unroll
    for (int p = 0; p < NP; ++p) {
        const float4 tl = base[(size_t)(CF + p) * PQ + rem];
        float4* dst = (float4*)(F + ((size_t)(b * NP + p) * PLANE_SZ + 4 * rem) * 2);
        float4 o0 = {acc.x, tl.x, acc.y, tl.y};
        float4 o1 = {acc.z, tl.z, acc.w, tl.w};
        dst[0] = o0;
        dst[1] = o1;
    }
}

// ---------------- Kernel A2: coords repack to part-major ----------------
__global__ void tp_repack_kernel(const float* __restrict__ coords,
                                 const int* __restrict__ index,
                                 float4* __restrict__ Cp) {
    int tid = blockIdx.x * blockDim.x + threadIdx.x;  // [0, NPOINTS*NP)
    int gpoint = tid / NP;
    int part = tid - gpoint * NP;
    int row = index[gpoint] * NP + part;
    float4 v;
    v.x = coords[row * 3 + 0];
    v.y = coords[row * 3 + 1];
    v.z = coords[row * 3 + 2];
    v.w = 0.f;
    Cp[(size_t)part * NPOINTS + gpoint] = v;
}

// Fused-plane corner-pair sample: texel = float2(mean, logit). One aligned
// float4 covers texels (xa, xa+1); predicated float2 only for odd-x0 interior.
__device__ __forceinline__ void sample_fused(const float* __restrict__ P,
                                             int r, int x0, int x1,
                                             float& m0, float& t0,
                                             float& m1, float& t1) {
    const int xa = x0 & ~1;
    const float4 v = *reinterpret_cast<const float4*>(P + 2 * (r + xa));
    if (x0 & 1) {
        m0 = v.z; t0 = v.w;
        if (x1 == x0) { m1 = m0; t1 = t0; }          // right edge (255)
        else {
            const float2 w = *reinterpret_cast<const float2*>(P + 2 * (r + x1));
            m1 = w.x; t1 = w.y;
        }
    } else {
        m0 = v.x; t0 = v.y;
        if (x1 == x0) { m1 = m0; t1 = t0; }          // left edge (0)
        else { m1 = v.z; t1 = v.w; }
    }
}

// ---------------- Kernel B: gather from fused planes ----------------
// 1024 blocks x 256 threads = 4 blocks/CU (16 waves/CU). XCD = blockIdx%8
// owns batch b = xcd/2 and 12 parts; 4 concurrent part-streams x 3 loop
// iterations. Live set per XCD ~ 4 fused planes (6 MB) + L3 holds all of F.
__global__ __launch_bounds__(256) void tp_gather_kernel(
    const float* __restrict__ F, const float4* __restrict__ Cp,
    float* __restrict__ wfeat, float* __restrict__ wlog) {
    const int xcd = blockIdx.x & 7;
    const int idx = blockIdx.x >> 3;   // 0..127
    const int b = xcd >> 1;
    const int pslot = idx & 3;         // 4 concurrent part-streams
    const int chunk = idx >> 2;        // 0..31 (256 points each)
    const int gpoint = b * NPTS + chunk * 256 + threadIdx.x;

    for (int gg = 0; gg < 3; ++gg) {
        const int part = (xcd & 1) * 12 + gg * 4 + pslot;
        const float4 c4 = Cp[(size_t)part * NPOINTS + gpoint];
        const float x = c4.x, y = c4.y, z = c4.z;
        const float us[3] = {x, x, y};
        const float vs[3] = {y, z, z};
        const float* __restrict__ Fp = F + (size_t)(b * NP + part) * PLANE_SZ * 2;

        float feat = 0.f, lg = 0.f;
#pragma unroll
        for (int k = 0; k < 3; ++k) {
            const float px = (us[k] + 1.0f) * (HS * 0.5f) - 0.5f;
            const float py = (vs[k] + 1.0f) * (HS * 0.5f) - 0.5f;
            const float x0f = floorf(px);
            const float y0f = floorf(py);
            const float wx = px - x0f;
            const float wy = py - y0f;
            const int x0i = (int)x0f;
            const int y0i = (int)y0f;
            const int x0 = min(max(x0i, 0), HS - 1);
            const int x1 = min(max(x0i + 1, 0), HS - 1);
            const int y0 = min(max(y0i, 0), HS - 1);
            const int y1 = min(max(y0i + 1, 0), HS - 1);
            const float w00 = (1.f - wx) * (1.f - wy);
            const float w01 = wx * (1.f - wy);
            const float w10 = (1.f - wx) * wy;
            const float w11 = wx * wy;

            const int r0 = y0 * W3 + k * HS;
            const int r1 = y1 * W3 + k * HS;

            float m00, t00, m01, t01, m10, t10, m11, t11;
            sample_fused(Fp, r0, x0, x1, m00, t00, m01, t01);
            sample_fused(Fp, r1, x0, x1, m10, t10, m11, t11);

            feat += m00 * w00 + m01 * w01 + m10 * w10 + m11 * w11;
            lg   += t00 * w00 + t01 * w01 + t10 * w10 + t11 * w11;
        }

        wfeat[(size_t)part * NPOINTS + gpoint] = feat;
        wlog[(size_t)part * NPOINTS + gpoint] = lg;
    }
}

// ---------------- Kernel C: softmax-combine over parts ----------------
__global__ __launch_bounds__(256) void tp_softmax_kernel(
    const float* __restrict__ wfeat, const float* __restrict__ wlog,
    float* __restrict__ out) {
    const int gpoint = blockIdx.x * 256 + threadIdx.x;  // [0, NPOINTS)
    float f[NP], l[NP];
#pragma unroll
    for (int p = 0; p < NP; ++p) {
        f[p] = wfeat[(size_t)p * NPOINTS + gpoint];
        l[p] = wlog[(size_t)p * NPOINTS + gpoint];
    }
    float mx = -1e30f;
#pragma unroll
    for (int p = 0; p < NP; ++p) mx = fmaxf(mx, l[p]);
    float se = 0.f, acc = 0.f;
#pragma unroll
    for (int p = 0; p < NP; ++p) {
        const float e = __expf(l[p] - mx);
        se += e;
        acc += e * f[p];
    }
    out[gpoint] = acc / se;
}

extern "C" void kernel_launch(void* const* d_in, const int* in_sizes, int n_in,
                              void* d_out, int out_size, void* d_ws, size_t ws_size,
                              hipStream_t stream) {
    const float* tri = (const float*)d_in[0];
    const float* coords = (const float*)d_in[1];
    const int* index = (const int*)d_in[2];
    float* out = (float*)d_out;

    // Workspace layout (floats):
    float* F = (float*)d_ws;                         // 4*24*PLANE_SZ*2 = 37.7M f (151 MB)
    float4* Cp = (float4*)(F + (size_t)4 * NP * PLANE_SZ * 2);  // 786432 float4 (12 MB)
    float* wfeat = (float*)(Cp + NP * NPOINTS);      // 786432 floats
    float* wlog = wfeat + NP * NPOINTS;              // 786432 floats

    tp_fuse_kernel<<<(4 * PQ) / 256, 256, 0, stream>>>(tri, F);
    tp_repack_kernel<<<(NPOINTS * NP) / 256, 256, 0, stream>>>(coords, index, Cp);
    tp_gather_kernel<<<1024, 256, 0, stream>>>(F, Cp, wfeat, wlog);
    tp_softmax_kernel<<<NPOINTS / 256, 256, 0, stream>>>(wfeat, wlog, out);
}